// Round 3
// baseline (4987.546 us; speedup 1.0000x reference)
//
// T-LSTM persistent-recurrence kernel for MI355X (gfx950) — round 5.
//
// Round 4 post-mortem: harness exception == kernel hang. Root cause
// candidate: the global all-256 startup barrier assumed full grid
// co-residency, which normal launches do NOT guarantee (rounds 2-3 only
// needed per-group residency). Fix: hipLaunchCooperativeKernel (guaranteed
// co-residency or launch error), with a host-side fallback to a normal
// launch that skips negotiation entirely (allow_local=0 -> proven round-3
// agent-scope path). Negotiation hardened: per-WG test words, guards on
// all spins, unanimous veto on any anomaly.
//
// LOCAL mode (XCD-shared L2 communication): each WG reads HW_REG_XCC_ID,
// claims a slot; if all 8 XCDs got exactly 32 WGs and every WG's plain
// store is visible to its groupmates' sc0 loads (self-test), groups remap
// to XCDs and all state/flag exchange runs through the shared per-XCD L2
// (~250 cy round trips) instead of MALL (~700-900 cy).

#include <hip/hip_runtime.h>

typedef unsigned short u16;
typedef unsigned int u32;
typedef unsigned long long u64;
typedef __attribute__((ext_vector_type(8))) short short8;
typedef __attribute__((ext_vector_type(4))) float f32x4;
typedef __attribute__((ext_vector_type(4))) unsigned int u32x4;

constexpr int BATCH = 128, SEQ = 512, ISZ = 256, HSZ = 512, G4H = 2048;
constexpr int KZ   = ISZ + HSZ;                 // 768
constexpr int NGRP = 8,  MR  = BATCH / NGRP;    // 16 rows per group
constexpr int NCW  = 32, CPW = HSZ / NCW;       // 16 cols per WG
constexpr int LDBZ = KZ + 8, LDBC = HSZ + 8, LDH = HSZ + 8;
constexpr int BH   = BATCH * HSZ;               // 65536
constexpr size_t BSH = (size_t)BATCH * SEQ * HSZ;

// workspace layout (bytes)
constexpr size_t WUT_OFF = 0;                                  // 2048*768*2
constexpr size_t WDT_OFF = WUT_OFF + (size_t)G4H * KZ * 2;     // 512*512*2
constexpr size_t HBF_OFF = WDT_OFF + (size_t)HSZ * HSZ * 2;    // h bf16 x2
constexpr size_t CBF_OFF = HBF_OFF + (size_t)2 * BH * 2;       // c bf16 x2
constexpr size_t FLG_OFF = CBF_OFF + (size_t)2 * BH * 2;       // 256+512 ints

// LDS layout (bytes)
constexpr int BZ_OFF  = 0;                       // [64][LDBZ] u16
constexpr int BC_OFF  = BZ_OFF  + 64 * LDBZ * 2; // [16][LDBC] u16
constexpr int HS_OFF  = BC_OFF  + 16 * LDBC * 2; // [MR][LDH]  u16
constexpr int ZS_OFF  = HS_OFF  + MR * LDH * 2;  // [5][16][16] f32
constexpr int CFL_OFF = ZS_OFF  + 5 * 256 * 4;   // [16][16] f32
constexpr int BL_OFF  = CFL_OFF + MR * CPW * 4;  // [5][16] f32
constexpr int LDS_BYTES = BL_OFF + 5 * CPW * 4;  // 139072

// ctl[] (= flags + 256): 0..7 per-XCD slot counters, 8 arrive1, 9 arrive2,
// 10 vote (init 1), 12 arrive3, 64..319 per-WG test words (group g owns
// ints [64+32g, 96+32g) — 128B line-exclusive, never touched by agent ops
// during the test window).

__device__ __forceinline__ u16 f2bf(float f) {
  unsigned u = __float_as_uint(f);
  u += 0x7fffu + ((u >> 16) & 1u);   // RNE
  return (u16)(u >> 16);
}

__device__ __forceinline__ u32 cvtpk(float lo, float hi) {
  u32 r;
  asm("v_cvt_pk_bf16_f32 %0, %1, %2" : "=v"(r) : "v"(lo), "v"(hi));
  return r;
}

__device__ __forceinline__ short8 cvt_bf8(float4 a, float4 b) {
  union { u32 u[4]; short8 s; } v;
  v.u[0] = cvtpk(a.x, a.y);
  v.u[1] = cvtpk(a.z, a.w);
  v.u[2] = cvtpk(b.x, b.y);
  v.u[3] = cvtpk(b.z, b.w);
  return v.s;
}

__device__ __forceinline__ u64 ld_at64(const void* p) {
  return __hip_atomic_load((const u64*)p, __ATOMIC_RELAXED,
                           __HIP_MEMORY_SCOPE_AGENT);
}
__device__ __forceinline__ void st_at64(void* p, u64 v) {
  __hip_atomic_store((u64*)p, v, __ATOMIC_RELAXED, __HIP_MEMORY_SCOPE_AGENT);
}
__device__ __forceinline__ void st_at32(void* p, u32 v) {
  __hip_atomic_store((u32*)p, v, __ATOMIC_RELAXED, __HIP_MEMORY_SCOPE_AGENT);
}
__device__ __forceinline__ int ld_ati(const int* p) {
  return __hip_atomic_load(p, __ATOMIC_RELAXED, __HIP_MEMORY_SCOPE_AGENT);
}

// ---- mode-templated state/flag ops ----
template<bool LOCAL>
__device__ __forceinline__ u64 ld64g(const u64* p) {
  if constexpr (LOCAL) {
    u64 r;
    asm volatile("global_load_dwordx2 %0, %1, off sc0" : "=v"(r) : "v"(p));
    return r;
  } else {
    return ld_at64(p);
  }
}

template<bool LOCAL>
__device__ __forceinline__ short8 ld128g(const u16* p) {
  if constexpr (LOCAL) {
    union { u32x4 u; short8 s; } r;
    asm volatile("global_load_dwordx4 %0, %1, off sc0" : "=v"(r.u) : "v"(p));
    return r.s;
  } else {
    union { u64 u[2]; short8 s; } v;
    v.u[0] = ld_at64(p);
    v.u[1] = ld_at64(p + 4);
    return v.s;
  }
}

template<bool LOCAL>
__device__ __forceinline__ void wait_vm0() {
  if constexpr (LOCAL) {
    asm volatile("s_waitcnt vmcnt(0)" ::: "memory");
    __builtin_amdgcn_sched_barrier(0);
  }
}

template<bool LOCAL>
__device__ __forceinline__ int ldflag(const int* p) {
  if constexpr (LOCAL) {
    int r;
    asm volatile("global_load_dword %0, %1, off sc0\n\ts_waitcnt vmcnt(0)"
                 : "=v"(r) : "v"(p) : "memory");
    return r;
  } else {
    return ld_ati(p);
  }
}

template<bool LOCAL>
__device__ __forceinline__ void stflag(int* p, int v) {
  if constexpr (LOCAL) {
    asm volatile("global_store_dword %0, %1, off" :: "v"(p), "v"(v) : "memory");
  } else {
    __hip_atomic_store(p, v, __ATOMIC_RELAXED, __HIP_MEMORY_SCOPE_AGENT);
  }
}

__device__ __forceinline__ float sig_f(float x)  { return 1.f / (1.f + __expf(-x)); }
__device__ __forceinline__ float tanh_f(float x) { return 1.f - 2.f / (1.f + __expf(2.f * x)); }

// guarded agent-scope spin: returns 1 on success, 0 on guard expiry
__device__ __forceinline__ int spin_ctl(int* p, int target) {
  for (int i = 0; i < (1 << 18); ++i) {
    if (ld_ati(p) >= target) return 1;
    __builtin_amdgcn_s_sleep(8);
  }
  return 0;
}

// ---- prep: tiled transpose W||U -> wut, Wd -> wdt; ctl/flags init ----
constexpr int TJ1 = G4H / 32;       // 64
constexpr int TK1 = KZ / 32;        // 24
constexpr int NT1 = TJ1 * TK1;      // 1536
constexpr int TJ2 = HSZ / 32;       // 16
constexpr int NT2 = TJ2 * TJ2;      // 256

__global__ void tlstm_prep(const float* __restrict__ W, const float* __restrict__ U,
                           const float* __restrict__ Wd,
                           u16* __restrict__ wut, u16* __restrict__ wdt,
                           int* __restrict__ flags) {
  __shared__ float tb[32][33];
  const int tid = threadIdx.x;
  const int c = tid & 31, r = tid >> 5;
  const int tile = blockIdx.x;
  int* ctl = flags + 256;
  if (tile == 0 && tid < 256) flags[tid] = 0;
  if ((tile == 1 || tile == 2) && tid < 256) {
    int i = (tile - 1) * 256 + tid;
    ctl[i] = (i == 10) ? 1 : 0;                 // vote starts at 1
  }
  if (tile < NT1) {
    const int tj = tile % TJ1, tk = tile / TJ1;
    const int j0 = tj * 32, k0 = tk * 32;
#pragma unroll
    for (int rr = r; rr < 32; rr += 8) {
      const int k = k0 + rr;
      tb[rr][c] = (k < ISZ) ? W[(size_t)k * G4H + j0 + c]
                            : U[(size_t)(k - ISZ) * G4H + j0 + c];
    }
    __syncthreads();
#pragma unroll
    for (int rr = r; rr < 32; rr += 8)
      wut[(size_t)(j0 + rr) * KZ + k0 + c] = f2bf(tb[c][rr]);
  } else {
    const int t2 = tile - NT1;
    const int tj = t2 % TJ2, tk = t2 / TJ2;
    const int j0 = tj * 32, k0 = tk * 32;
#pragma unroll
    for (int rr = r; rr < 32; rr += 8)
      tb[rr][c] = Wd[(size_t)(k0 + rr) * HSZ + j0 + c];
    __syncthreads();
#pragma unroll
    for (int rr = r; rr < 32; rr += 8)
      wdt[(size_t)(j0 + rr) * HSZ + k0 + c] = f2bf(tb[c][rr]);
  }
}

// ---- the persistent recurrence loop, templated on communication mode ----
template<bool LOCAL>
__device__ __forceinline__ void run_loop(
    const float* __restrict__ x, const float* __restrict__ dtp,
    u16* hbf, u16* cbf, int* flags, float* out,
    char* lds, const int tid, const int grp, const int cwg) {
  u16*   Bz  = (u16*)(lds + BZ_OFF);
  u16*   Bc  = (u16*)(lds + BC_OFF);
  u16*   hs  = (u16*)(lds + HS_OFF);
  float* zs  = (float*)(lds + ZS_OFF);
  float* cfl = (float*)(lds + CFL_OFF);
  float* bl  = (float*)(lds + BL_OFF);

  const int G0   = grp * MR;
  const int C0   = cwg * CPW;
  const int wave = tid >> 6, lane = tid & 63;
  const int m16  = lane & 15, quad = lane >> 4;
  const int* fbase = flags + grp * 32;
  const float* xbase = x + (size_t)(G0 + m16) * SEQ * ISZ + quad * 8;
  const int drow = G0 + (tid >> 3);

  // prologue prefetch for t = 0
  short8 xa8[8];
  float dtn = 0.f;
  if (wave < 4) {
    float4 xf[16];
#pragma unroll
    for (int kt = 0; kt < 8; ++kt) {
      xf[2 * kt]     = *(const float4*)(xbase + kt * 32);
      xf[2 * kt + 1] = *(const float4*)(xbase + kt * 32 + 4);
    }
#pragma unroll
    for (int kt = 0; kt < 8; ++kt)
      xa8[kt] = cvt_bf8(xf[2 * kt], xf[2 * kt + 1]);
  }
  if (tid < 128) dtn = dtp[(size_t)drow * SEQ];

  for (int t = 0; t < SEQ; ++t) {
    const int p = t & 1, q = p ^ 1;
    const u16* hA = hbf + (size_t)p * BH;
    const u16* cA = cbf + (size_t)p * BH;
    u16* hQ = hbf + (size_t)q * BH;
    u16* cQ = cbf + (size_t)q * BH;
    const float dtv = dtn;

    f32x4 acc = {0.f, 0.f, 0.f, 0.f};

    if (wave < 4) {
      // issue h loads, then x-GEMM (pure reg/LDS) covers the latency
      const u64* src = (const u64*)(hA + (size_t)G0 * HSZ);
      u64 hv[8];
#pragma unroll
      for (int j = 0; j < 8; ++j)
        hv[j] = ld64g<LOCAL>(src + tid + j * 256);

      const u16* bz = Bz + (size_t)(wave * 16 + m16) * LDBZ + quad * 8;
#pragma unroll
      for (int kt = 0; kt < 8; ++kt) {
        short8 b = *(const short8*)(bz + kt * 32);
        acc = __builtin_amdgcn_mfma_f32_16x16x32_bf16(xa8[kt], b, acc, 0, 0, 0);
      }
      wait_vm0<LOCAL>();
      u64* dst = (u64*)hs;
#pragma unroll
      for (int j = 0; j < 8; ++j) {
        int i = tid + j * 256;
        dst[(i >> 7) * (LDH / 4) + (i & 127)] = hv[j];
      }
    } else {
      // c_s wave: batched c loads, then GEMM vs Bc
      const u16* cp = cA + (size_t)(G0 + m16) * HSZ + quad * 8;
      short8 ca[16];
#pragma unroll
      for (int kt = 0; kt < 16; ++kt)
        ca[kt] = ld128g<LOCAL>(cp + kt * 32);
      wait_vm0<LOCAL>();
      const u16* bc = Bc + (size_t)m16 * LDBC + quad * 8;
#pragma unroll
      for (int kt = 0; kt < 16; ++kt) {
        short8 b = *(const short8*)(bc + kt * 32);
        acc = __builtin_amdgcn_mfma_f32_16x16x32_bf16(ca[kt], b, acc, 0, 0, 0);
      }
#pragma unroll
      for (int i = 0; i < 4; ++i)
        zs[4 * 256 + (quad * 4 + i) * 16 + m16] = acc[i];
    }
    __syncthreads();   // hs staged (+ zs[4] written)

    if (wave < 4) {
      const u16* bz2 = Bz + (size_t)(wave * 16 + m16) * LDBZ + 256 + quad * 8;
      const u16* hp  = hs + (size_t)m16 * LDH + quad * 8;
#pragma unroll
      for (int kt = 0; kt < 16; ++kt) {
        short8 a = *(const short8*)(hp + kt * 32);
        short8 b = *(const short8*)(bz2 + kt * 32);
        acc = __builtin_amdgcn_mfma_f32_16x16x32_bf16(a, b, acc, 0, 0, 0);
      }
#pragma unroll
      for (int i = 0; i < 4; ++i)
        zs[wave * 256 + (quad * 4 + i) * 16 + m16] = acc[i];
    }
    __syncthreads();   // zs complete

    float rh0 = 0.f, rh1 = 0.f, rc0 = 0.f, rc1 = 0.f;
    int row = 0, ch = 0;
    if (tid < 128) {
      const int lr  = tid >> 3;
      const int cp2 = (tid & 7) * 2;
      row = G0 + lr;
      ch  = C0 + cp2;
      const float gdec = 1.f / __logf(2.718281828459045f + dtv);
      float rh[2], rc[2];
#pragma unroll
      for (int u = 0; u < 2; ++u) {
        const int c = cp2 + u;
        const int zb = lr * 16 + c;
        float zi = zs[0 * 256 + zb] + bl[0 * 16 + c];
        float zf = zs[1 * 256 + zb] + bl[1 * 16 + c];
        float zo = zs[2 * 256 + zb] + bl[2 * 16 + c];
        float zc = zs[3 * 256 + zb] + bl[3 * 16 + c];
        float s  = zs[4 * 256 + zb] + bl[4 * 16 + c];
        float cprev = cfl[zb];
        float cs = tanh_f(s);
        float cadj = cprev - cs + cs * gdec;
        float ig = sig_f(zi), fg = sig_f(zf), og = sig_f(zo);
        float ct = tanh_f(zc);
        float cnew = fg * cadj + ig * ct;
        float hnew = og * tanh_f(cnew);
        cfl[zb] = cnew;
        rh[u] = hnew; rc[u] = cnew;
      }
      rh0 = rh[0]; rh1 = rh[1]; rc0 = rc[0]; rc1 = rc[1];
      if constexpr (LOCAL) {
        *(u32*)(hQ + (size_t)row * HSZ + ch) = cvtpk(rh0, rh1);
        *(u32*)(cQ + (size_t)row * HSZ + ch) = cvtpk(rc0, rc1);
      } else {
        st_at32(hQ + (size_t)row * HSZ + ch, cvtpk(rh0, rh1));
        st_at32(cQ + (size_t)row * HSZ + ch, cvtpk(rc0, rc1));
      }
    }

    if (t < SEQ - 1) {
      __syncthreads();   // state stores drained (vmcnt 0)
      __asm__ volatile("" ::: "memory");
      if (tid == 0)
        stflag<LOCAL>(&flags[grp * 32 + cwg], t + 2);
      // off the critical path: hide under the spin
      if (tid < 128) {
        float2 hv2; hv2.x = rh0; hv2.y = rh1;
        *(float2*)(out + ((size_t)row * SEQ + t) * HSZ + ch) = hv2;
      }
      if (wave < 4) {
        const float* xn = xbase + (size_t)(t + 1) * ISZ;
        float4 xf[16];
#pragma unroll
        for (int kt = 0; kt < 8; ++kt) {
          xf[2 * kt]     = *(const float4*)(xn + kt * 32);
          xf[2 * kt + 1] = *(const float4*)(xn + kt * 32 + 4);
        }
#pragma unroll
        for (int kt = 0; kt < 8; ++kt)
          xa8[kt] = cvt_bf8(xf[2 * kt], xf[2 * kt + 1]);
      }
      if (tid < 128)
        dtn = dtp[(size_t)drow * SEQ + t + 1];
      for (int gu = 0; ; ++gu) {
        int v = (lane < 32) ? ldflag<LOCAL>(fbase + lane) : 0x7fffffff;
        if (__all(v >= t + 2)) break;
        if (gu > (1 << 22)) break;      // hang insurance: fail visibly
        __builtin_amdgcn_s_sleep(1);
      }
      __asm__ volatile("" ::: "memory");
    } else {
      if (tid < 128) {
        float2 hv2; hv2.x = rh0; hv2.y = rh1;
        float2 cv2; cv2.x = rc0; cv2.y = rc1;
        *(float2*)(out + ((size_t)row * SEQ + t) * HSZ + ch) = hv2;
        *(float2*)(out + BSH + (size_t)row * HSZ + ch) = hv2;       // h_t
        *(float2*)(out + BSH + BH + (size_t)row * HSZ + ch) = cv2;  // c_t
      }
    }
  }
}

__global__ void __launch_bounds__(320, 1)
tlstm_rec(const float* __restrict__ x, const float* __restrict__ dtp,
          const float* __restrict__ bias, const float* __restrict__ bd,
          const u16* __restrict__ wut, const u16* __restrict__ wdt,
          u16* hbf, u16* cbf, int* flags, float* out, int allow_local) {
  extern __shared__ char lds[];
  __shared__ int sh[3];
  const int tid = threadIdx.x;
  int* ctl = flags + 256;

  // ---- mode negotiation (only under cooperative launch) ----
  if (tid == 0) {
    int g = blockIdx.x >> 5, c = blockIdx.x & 31, mode = 0;
    if (allow_local) {
      u32 xcc;
      asm volatile("s_getreg_b32 %0, hwreg(20, 0, 32)" : "=s"(xcc));
      const int myx = (int)(xcc & 7u);
      const int slot = __hip_atomic_fetch_add(&ctl[myx], 1, __ATOMIC_RELAXED,
                                              __HIP_MEMORY_SCOPE_AGENT);
      __hip_atomic_fetch_add(&ctl[8], 1, __ATOMIC_RELAXED,
                             __HIP_MEMORY_SCOPE_AGENT);
      int ok1 = spin_ctl(&ctl[8], 256);
      bool bal = (ok1 != 0);
      if (bal)
        for (int i = 0; i < 8; ++i)
          bal &= (ld_ati(&ctl[i]) == 32);
      if (bal && slot < 32) {
        // write OWN test word (plain store -> dirty in this XCD's L2)
        int* tw = &ctl[64 + myx * 32 + slot];
        int mg = 0x5A130000 | (myx << 8) | slot;
        asm volatile("global_store_dword %0, %1, off\n\ts_waitcnt vmcnt(0)"
                     :: "v"(tw), "v"(mg) : "memory");
      } else {
        __hip_atomic_fetch_and(&ctl[10], 0, __ATOMIC_RELAXED,
                               __HIP_MEMORY_SCOPE_AGENT);
      }
      __hip_atomic_fetch_add(&ctl[9], 1, __ATOMIC_RELAXED,
                             __HIP_MEMORY_SCOPE_AGENT);
      if (!spin_ctl(&ctl[9], 256)) bal = false;
      if (bal) {
        // verify ALL groupmates' plain stores visible via sc0 loads
        int ok = 1;
        for (int i = 0; i < 32; ++i) {
          int tv;
          const int* tp = &ctl[64 + myx * 32 + i];
          asm volatile("global_load_dword %0, %1, off sc0\n\ts_waitcnt vmcnt(0)"
                       : "=v"(tv) : "v"(tp) : "memory");
          ok &= (tv == (0x5A130000 | (myx << 8) | i));
        }
        if (!ok)
          __hip_atomic_fetch_and(&ctl[10], 0, __ATOMIC_RELAXED,
                                 __HIP_MEMORY_SCOPE_AGENT);
      }
      __hip_atomic_fetch_add(&ctl[12], 1, __ATOMIC_RELAXED,
                             __HIP_MEMORY_SCOPE_AGENT);
      if (!spin_ctl(&ctl[12], 256)) bal = false;
      mode = bal ? ld_ati(&ctl[10]) : 0;
      if (mode) { g = myx; c = slot; }
    }
    sh[0] = g; sh[1] = c; sh[2] = mode;
  }
  __syncthreads();
  const int grp = sh[0], cwg = sh[1], mode = sh[2];
  const int G0 = grp * MR, C0 = cwg * CPW;

  u16*   Bz  = (u16*)(lds + BZ_OFF);
  u16*   Bc  = (u16*)(lds + BC_OFF);
  float* cfl = (float*)(lds + CFL_OFF);
  float* bl  = (float*)(lds + BL_OFF);

  // ---- stage weights into LDS (once) ----
  {
    const unsigned* src = (const unsigned*)wut;
    unsigned* dst = (unsigned*)Bz;
    for (int i = tid; i < 64 * (KZ / 2); i += 320) {
      int gc = i / (KZ / 2), d = i - gc * (KZ / 2);
      int zc = (gc >> 4) * HSZ + C0 + (gc & 15);   // gate-major z column
      dst[gc * (LDBZ / 2) + d] = src[zc * (KZ / 2) + d];
    }
    const unsigned* s2 = (const unsigned*)wdt;
    unsigned* d2 = (unsigned*)Bc;
    for (int i = tid; i < 16 * (HSZ / 2); i += 320) {
      int r = i >> 8, d = i & 255;
      d2[r * (LDBC / 2) + d] = s2[(C0 + r) * (HSZ / 2) + d];
    }
  }
  if (tid < 80) {
    int j = tid >> 4, c = tid & 15;
    bl[tid] = (j < 4) ? bias[j * HSZ + C0 + c] : bd[C0 + c];
  }
  if (tid < 256) cfl[tid] = 0.f;
  // zero group's state rows in buffer 0 (agent stores -> at MALL; LOCAL
  // t=0 sc0 loads miss L2 and fetch zeros from MALL)
  {
    u64* h0 = (u64*)(hbf + (size_t)G0 * HSZ);
    u64* c0 = (u64*)(cbf + (size_t)G0 * HSZ);
    for (int i = tid; i < MR * HSZ / 4; i += 320) {
      st_at64(h0 + i, 0ull);
      st_at64(c0 + i, 0ull);
    }
  }
  __syncthreads();   // zeros drained before t=0 reads

  if (mode)
    run_loop<true>(x, dtp, hbf, cbf, flags, out, lds, tid, grp, cwg);
  else
    run_loop<false>(x, dtp, hbf, cbf, flags, out, lds, tid, grp, cwg);
}

extern "C" void kernel_launch(void* const* d_in, const int* in_sizes, int n_in,
                              void* d_out, int out_size, void* d_ws, size_t ws_size,
                              hipStream_t stream) {
  (void)in_sizes; (void)n_in; (void)out_size; (void)ws_size;
  const float* x  = (const float*)d_in[0];
  const float* dt = (const float*)d_in[1];
  const float* W  = (const float*)d_in[2];
  const float* U  = (const float*)d_in[3];
  const float* b  = (const float*)d_in[4];
  const float* Wd = (const float*)d_in[5];
  const float* bd = (const float*)d_in[6];
  float* out = (float*)d_out;
  char*  ws  = (char*)d_ws;

  u16* wut   = (u16*)(ws + WUT_OFF);
  u16* wdt   = (u16*)(ws + WDT_OFF);
  u16* hbf   = (u16*)(ws + HBF_OFF);
  u16* cbf   = (u16*)(ws + CBF_OFF);
  int* flags = (int*)(ws + FLG_OFF);

  tlstm_prep<<<NT1 + NT2, 256, 0, stream>>>(W, U, Wd, wut, wdt, flags);

  hipFuncSetAttribute((const void*)tlstm_rec,
                      hipFuncAttributeMaxDynamicSharedMemorySize, LDS_BYTES);

  int allow = 1;
  void* args[11] = {(void*)&x, (void*)&dt, (void*)&b, (void*)&bd,
                    (void*)&wut, (void*)&wdt, (void*)&hbf, (void*)&cbf,
                    (void*)&flags, (void*)&out, (void*)&allow};
  hipError_t e = hipLaunchCooperativeKernel((const void*)tlstm_rec,
                                            dim3(NGRP * NCW), dim3(320),
                                            args, LDS_BYTES, stream);
  if (e != hipSuccess) {
    (void)hipGetLastError();   // clear error state
    // normal launch: skip negotiation entirely (proven agent-scope path,
    // safe under partial residency)
    tlstm_rec<<<NGRP * NCW, 320, LDS_BYTES, stream>>>(
        x, dt, b, bd, wut, wdt, hbf, cbf, flags, out, 0);
  }
}

// Round 4
// 4642.038 us; speedup vs baseline: 1.0744x; 1.0744x over previous
//
// T-LSTM persistent-recurrence kernel for MI355X (gfx950) — round 6.
//
// Round 5 post-mortem: XCD-local (L2) communication ENGAGED (FETCH 792->48
// MB proves it) yet ran 57% SLOWER than the agent/MALL path. L2-local
// round trips are not faster for this handshake -> mechanism reverted.
//
// Round 6: amortize + hide the (irreducible) MALL latency via GROUP
// PAIRING. 4 pairs x 32 col-WGs = 128 WGs; each WG serves two batch
// groups (p, p+4) with the SAME 16 columns, so the LDS weight tiles are
// shared. Per iteration: one poll + one load-issue covers BOTH groups;
// group A's flag is stored mid-iteration (after a __syncthreads drain)
// and propagates while group B computes, so peers' polls wait on B only.
// Intra-iteration barriers use raw s_barrier + lgkmcnt(0) (no vmem-ack
// drain on the chain); only the two pre-flag barriers fully drain.
// Cell fp32 master state lives in registers (thread-private).

#include <hip/hip_runtime.h>

typedef unsigned short u16;
typedef unsigned int u32;
typedef unsigned long long u64;
typedef __attribute__((ext_vector_type(8))) short short8;
typedef __attribute__((ext_vector_type(4))) float f32x4;

constexpr int BATCH = 128, SEQ = 512, ISZ = 256, HSZ = 512, G4H = 2048;
constexpr int KZ   = ISZ + HSZ;                 // 768
constexpr int NGRP = 8,  MR  = BATCH / NGRP;    // 16 rows per group
constexpr int NCW  = 32, CPW = HSZ / NCW;       // 16 cols per WG
constexpr int NPAIR = 4;                        // groups (p, p+4)
constexpr int LDBZ = KZ + 8, LDBC = HSZ + 8, LDH = HSZ + 8;
constexpr int BH   = BATCH * HSZ;               // 65536
constexpr size_t BSH = (size_t)BATCH * SEQ * HSZ;

// workspace layout (bytes)
constexpr size_t WUT_OFF = 0;                                  // 2048*768*2
constexpr size_t WDT_OFF = WUT_OFF + (size_t)G4H * KZ * 2;     // 512*512*2
constexpr size_t HBF_OFF = WDT_OFF + (size_t)HSZ * HSZ * 2;    // h bf16 x2
constexpr size_t CBF_OFF = HBF_OFF + (size_t)2 * BH * 2;       // c bf16 x2
constexpr size_t FLG_OFF = CBF_OFF + (size_t)2 * BH * 2;       // 256 ints

// LDS layout (bytes)
constexpr int BZ_OFF  = 0;                        // [64][LDBZ] u16
constexpr int BC_OFF  = BZ_OFF  + 64 * LDBZ * 2;  // [16][LDBC] u16
constexpr int HSA_OFF = BC_OFF  + 16 * LDBC * 2;  // [MR][LDH]  u16 (grp A)
constexpr int HSB_OFF = HSA_OFF + MR * LDH * 2;   // [MR][LDH]  u16 (grp B)
constexpr int ZSA_OFF = HSB_OFF + MR * LDH * 2;   // [5][16][16] f32
constexpr int ZSB_OFF = ZSA_OFF + 5 * 256 * 4;    // [5][16][16] f32
constexpr int BL_OFF  = ZSB_OFF + 5 * 256 * 4;    // [5][16] f32
constexpr int LDS_BYTES = BL_OFF + 5 * CPW * 4;   // 159808 (<= 163840)

__device__ __forceinline__ u16 f2bf(float f) {
  unsigned u = __float_as_uint(f);
  u += 0x7fffu + ((u >> 16) & 1u);   // RNE
  return (u16)(u >> 16);
}

// hardware packed f32x2 -> bf16x2 (RNE), lo in bits [15:0]
__device__ __forceinline__ u32 cvtpk(float lo, float hi) {
  u32 r;
  asm("v_cvt_pk_bf16_f32 %0, %1, %2" : "=v"(r) : "v"(lo), "v"(hi));
  return r;
}

__device__ __forceinline__ short8 cvt_bf8(float4 a, float4 b) {
  union { u32 u[4]; short8 s; } v;
  v.u[0] = cvtpk(a.x, a.y);
  v.u[1] = cvtpk(a.z, a.w);
  v.u[2] = cvtpk(b.x, b.y);
  v.u[3] = cvtpk(b.z, b.w);
  return v.s;
}

__device__ __forceinline__ u64 ld_at64(const void* p) {
  return __hip_atomic_load((const u64*)p, __ATOMIC_RELAXED,
                           __HIP_MEMORY_SCOPE_AGENT);
}
__device__ __forceinline__ void st_at64(void* p, u64 v) {
  __hip_atomic_store((u64*)p, v, __ATOMIC_RELAXED, __HIP_MEMORY_SCOPE_AGENT);
}
__device__ __forceinline__ void st_at32(void* p, u32 v) {
  __hip_atomic_store((u32*)p, v, __ATOMIC_RELAXED, __HIP_MEMORY_SCOPE_AGENT);
}
__device__ __forceinline__ int ld_ati(const int* p) {
  return __hip_atomic_load(p, __ATOMIC_RELAXED, __HIP_MEMORY_SCOPE_AGENT);
}
__device__ __forceinline__ short8 ld_bf8_at(const u16* p) {
  union { u64 u[2]; short8 s; } v;
  v.u[0] = ld_at64(p);
  v.u[1] = ld_at64(p + 4);
  return v.s;
}

__device__ __forceinline__ float sig_f(float x)  { return 1.f / (1.f + __expf(-x)); }
__device__ __forceinline__ float tanh_f(float x) { return 1.f - 2.f / (1.f + __expf(2.f * x)); }

// raw barrier: LDS visibility only (no vmem-ack drain on the chain)
__device__ __forceinline__ void barl() {
  asm volatile("s_waitcnt lgkmcnt(0)" ::: "memory");
  __builtin_amdgcn_s_barrier();
  __builtin_amdgcn_sched_barrier(0);
}

// batched x-row fetch + bf16 convert (16 float4 issued back-to-back)
__device__ __forceinline__ void xfetch(const float* xp, short8* xa8) {
  float4 xf[16];
#pragma unroll
  for (int kt = 0; kt < 8; ++kt) {
    xf[2 * kt]     = *(const float4*)(xp + kt * 32);
    xf[2 * kt + 1] = *(const float4*)(xp + kt * 32 + 4);
  }
#pragma unroll
  for (int kt = 0; kt < 8; ++kt)
    xa8[kt] = cvt_bf8(xf[2 * kt], xf[2 * kt + 1]);
}

// per-thread T-LSTM cell update for 2 adjacent columns
__device__ __forceinline__ void tcell(const float* zsg, const float* bl,
    float dtv, int lr, int cp2, float& cprev0, float& cprev1,
    float& rh0, float& rh1, float& rc0, float& rc1) {
  const float gdec = 1.f / __logf(2.718281828459045f + dtv);
#pragma unroll
  for (int u = 0; u < 2; ++u) {
    const int c = cp2 + u;
    const int zb = lr * 16 + c;
    float zi = zsg[0 * 256 + zb] + bl[0 * 16 + c];
    float zf = zsg[1 * 256 + zb] + bl[1 * 16 + c];
    float zo = zsg[2 * 256 + zb] + bl[2 * 16 + c];
    float zc = zsg[3 * 256 + zb] + bl[3 * 16 + c];
    float s  = zsg[4 * 256 + zb] + bl[4 * 16 + c];
    float cprev = u ? cprev1 : cprev0;
    float cs = tanh_f(s);
    float cadj = cprev - cs + cs * gdec;
    float ig = sig_f(zi), fg = sig_f(zf), og = sig_f(zo);
    float ct = tanh_f(zc);
    float cnew = fg * cadj + ig * ct;
    float hnew = og * tanh_f(cnew);
    if (u) { cprev1 = cnew; rh1 = hnew; rc1 = cnew; }
    else   { cprev0 = cnew; rh0 = hnew; rc0 = cnew; }
  }
}

// ---- prep: tiled transpose W||U -> wut (2048x768 bf16), Wd -> wdt ----
constexpr int TJ1 = G4H / 32;       // 64
constexpr int TK1 = KZ / 32;        // 24
constexpr int NT1 = TJ1 * TK1;      // 1536
constexpr int TJ2 = HSZ / 32;       // 16
constexpr int NT2 = TJ2 * TJ2;      // 256

__global__ void tlstm_prep(const float* __restrict__ W, const float* __restrict__ U,
                           const float* __restrict__ Wd,
                           u16* __restrict__ wut, u16* __restrict__ wdt,
                           int* __restrict__ flags) {
  __shared__ float tb[32][33];
  const int tid = threadIdx.x;
  const int c = tid & 31, r = tid >> 5;       // 256 thr: r 0..7
  const int tile = blockIdx.x;
  if (tile == 0 && tid < 256) flags[tid] = 0; // deterministic sync state
  if (tile < NT1) {
    const int tj = tile % TJ1, tk = tile / TJ1;
    const int j0 = tj * 32, k0 = tk * 32;
#pragma unroll
    for (int rr = r; rr < 32; rr += 8) {
      const int k = k0 + rr;
      tb[rr][c] = (k < ISZ) ? W[(size_t)k * G4H + j0 + c]
                            : U[(size_t)(k - ISZ) * G4H + j0 + c];
    }
    __syncthreads();
#pragma unroll
    for (int rr = r; rr < 32; rr += 8)
      wut[(size_t)(j0 + rr) * KZ + k0 + c] = f2bf(tb[c][rr]);
  } else {
    const int t2 = tile - NT1;
    const int tj = t2 % TJ2, tk = t2 / TJ2;
    const int j0 = tj * 32, k0 = tk * 32;
#pragma unroll
    for (int rr = r; rr < 32; rr += 8)
      tb[rr][c] = Wd[(size_t)(k0 + rr) * HSZ + j0 + c];
    __syncthreads();
#pragma unroll
    for (int rr = r; rr < 32; rr += 8)
      wdt[(size_t)(j0 + rr) * HSZ + k0 + c] = f2bf(tb[c][rr]);
  }
}

__global__ void __launch_bounds__(320, 1)
tlstm_rec(const float* __restrict__ x, const float* __restrict__ dtp,
          const float* __restrict__ bias, const float* __restrict__ bd,
          const u16* __restrict__ wut, const u16* __restrict__ wdt,
          u16* hbf, u16* cbf, int* flags, float* out) {
  extern __shared__ char lds[];
  u16*   Bz  = (u16*)(lds + BZ_OFF);
  u16*   Bc  = (u16*)(lds + BC_OFF);
  u16*   hsA = (u16*)(lds + HSA_OFF);
  u16*   hsB = (u16*)(lds + HSB_OFF);
  float* zsA = (float*)(lds + ZSA_OFF);
  float* zsB = (float*)(lds + ZSB_OFF);
  float* bl  = (float*)(lds + BL_OFF);

  const int tid  = threadIdx.x;
  const int pid  = blockIdx.x >> 5;     // pair 0..3
  const int cwg  = blockIdx.x & 31;     // column WG 0..31
  const int gA   = pid, gB = pid + NPAIR;
  const int G0a  = gA * MR, G0b = gB * MR;
  const int C0   = cwg * CPW;
  const int wave = tid >> 6, lane = tid & 63;
  const int m16  = lane & 15, quad = lane >> 4;

  // ---- stage weights into LDS (once, shared by both groups) ----
  {
    const unsigned* src = (const unsigned*)wut;
    unsigned* dst = (unsigned*)Bz;
    for (int i = tid; i < 64 * (KZ / 2); i += 320) {
      int gc = i / (KZ / 2), d = i - gc * (KZ / 2);
      int zc = (gc >> 4) * HSZ + C0 + (gc & 15);   // gate-major z column
      dst[gc * (LDBZ / 2) + d] = src[zc * (KZ / 2) + d];
    }
    const unsigned* s2 = (const unsigned*)wdt;
    unsigned* d2 = (unsigned*)Bc;
    for (int i = tid; i < 16 * (HSZ / 2); i += 320) {
      int r = i >> 8, d = i & 255;
      d2[r * (LDBC / 2) + d] = s2[(C0 + r) * (HSZ / 2) + d];
    }
  }
  // biases -> LDS
  if (tid < 80) {
    int j = tid >> 4, c = tid & 15;
    bl[tid] = (j < 4) ? bias[j * HSZ + C0 + c] : bd[C0 + c];
  }
  // zero both groups' state rows in buffer 0 (all col-WGs write same zeros)
  {
    u64* h0a = (u64*)(hbf + (size_t)G0a * HSZ);
    u64* c0a = (u64*)(cbf + (size_t)G0a * HSZ);
    u64* h0b = (u64*)(hbf + (size_t)G0b * HSZ);
    u64* c0b = (u64*)(cbf + (size_t)G0b * HSZ);
    for (int i = tid; i < MR * HSZ / 4; i += 320) {
      st_at64(h0a + i, 0ull); st_at64(c0a + i, 0ull);
      st_at64(h0b + i, 0ull); st_at64(c0b + i, 0ull);
    }
  }
  __syncthreads();   // drains vmcnt: zeros at MALL before t=0 reads

  const float* xbA = x + (size_t)(G0a + m16) * SEQ * ISZ + quad * 8;
  const float* xbB = x + (size_t)(G0b + m16) * SEQ * ISZ + quad * 8;
  const int drA = G0a + (tid >> 3), drB = G0b + (tid >> 3);

  // prologue prefetch for t = 0
  short8 xa8a[8], xa8b[8];
  float dtnA = 0.f, dtnB = 0.f;
  if (wave < 4) { xfetch(xbA, xa8a); xfetch(xbB, xa8b); }
  if (tid < 128) { dtnA = dtp[(size_t)drA * SEQ]; dtnB = dtp[(size_t)drB * SEQ]; }
  // fp32 cell master state: thread-private registers
  float cpa0 = 0.f, cpa1 = 0.f, cpb0 = 0.f, cpb1 = 0.f;

  for (int t = 0; t < SEQ; ++t) {
    const int p = t & 1, q = p ^ 1;
    const u16* hP = hbf + (size_t)p * BH;
    const u16* cP = cbf + (size_t)p * BH;
    u16* hQ = hbf + (size_t)q * BH;
    u16* cQ = cbf + (size_t)q * BH;
    const float dtvA = dtnA, dtvB = dtnB;

    // ---- poll both groups' flags (peers completed step t-1) ----
    if (t > 0) {
      for (int gu = 0; ; ++gu) {
        int v = (lane < 32) ? ld_ati(flags + gA * 32 + lane)
                            : ld_ati(flags + gB * 32 + (lane - 32));
        if (__all(v >= t)) break;
        if (gu > (1 << 22)) break;      // hang insurance: fail visibly
        __builtin_amdgcn_s_sleep(1);
      }
      __asm__ volatile("" ::: "memory");
    }

    f32x4 acc  = {0.f, 0.f, 0.f, 0.f};
    f32x4 accB = {0.f, 0.f, 0.f, 0.f};
    short8 cb[16];

    if (wave < 4) {
      // one latency exposure: issue A AND B h loads back-to-back
      const u64* sA = (const u64*)(hP + (size_t)G0a * HSZ);
      const u64* sB = (const u64*)(hP + (size_t)G0b * HSZ);
      u64 ha[8], hb[8];
#pragma unroll
      for (int j = 0; j < 8; ++j) ha[j] = ld_at64(sA + tid + j * 256);
#pragma unroll
      for (int j = 0; j < 8; ++j) hb[j] = ld_at64(sB + tid + j * 256);
      // A x-GEMM (regs+LDS) while loads fly
      const u16* bz = Bz + (size_t)(wave * 16 + m16) * LDBZ + quad * 8;
#pragma unroll
      for (int kt = 0; kt < 8; ++kt) {
        short8 b = *(const short8*)(bz + kt * 32);
        acc = __builtin_amdgcn_mfma_f32_16x16x32_bf16(xa8a[kt], b, acc, 0, 0, 0);
      }
      // stage both h tiles
      u64* dA = (u64*)hsA; u64* dB = (u64*)hsB;
#pragma unroll
      for (int j = 0; j < 8; ++j) {
        int i = tid + j * 256;
        dA[(i >> 7) * (LDH / 4) + (i & 127)] = ha[j];
      }
#pragma unroll
      for (int j = 0; j < 8; ++j) {
        int i = tid + j * 256;
        dB[(i >> 7) * (LDH / 4) + (i & 127)] = hb[j];
      }
    } else {
      // c_s wave: A c loads -> GEMM -> zsA[4]; then issue B c loads
      const u16* cpA = cP + (size_t)(G0a + m16) * HSZ + quad * 8;
      short8 ca[16];
#pragma unroll
      for (int kt = 0; kt < 16; ++kt) ca[kt] = ld_bf8_at(cpA + kt * 32);
      const u16* bc = Bc + (size_t)m16 * LDBC + quad * 8;
#pragma unroll
      for (int kt = 0; kt < 16; ++kt) {
        short8 b = *(const short8*)(bc + kt * 32);
        acc = __builtin_amdgcn_mfma_f32_16x16x32_bf16(ca[kt], b, acc, 0, 0, 0);
      }
#pragma unroll
      for (int i = 0; i < 4; ++i)
        zsA[4 * 256 + (quad * 4 + i) * 16 + m16] = acc[i];
      const u16* cpB = cP + (size_t)(G0b + m16) * HSZ + quad * 8;
#pragma unroll
      for (int kt = 0; kt < 16; ++kt) cb[kt] = ld_bf8_at(cpB + kt * 32);
    }
    barl();   // BAR1: hsA/hsB staged, zsA[4] written (LDS only)

    if (wave < 4) {
      // A h@U from LDS
      const u16* bz2 = Bz + (size_t)(wave * 16 + m16) * LDBZ + 256 + quad * 8;
      const u16* hp  = hsA + (size_t)m16 * LDH + quad * 8;
#pragma unroll
      for (int kt = 0; kt < 16; ++kt) {
        short8 a = *(const short8*)(hp + kt * 32);
        short8 b = *(const short8*)(bz2 + kt * 32);
        acc = __builtin_amdgcn_mfma_f32_16x16x32_bf16(a, b, acc, 0, 0, 0);
      }
#pragma unroll
      for (int i = 0; i < 4; ++i)
        zsA[wave * 256 + (quad * 4 + i) * 16 + m16] = acc[i];
    } else {
      // B c_s GEMM (cb loads returned during BAR1 window)
      const u16* bc = Bc + (size_t)m16 * LDBC + quad * 8;
#pragma unroll
      for (int kt = 0; kt < 16; ++kt) {
        short8 b = *(const short8*)(bc + kt * 32);
        accB = __builtin_amdgcn_mfma_f32_16x16x32_bf16(cb[kt], b, accB, 0, 0, 0);
      }
#pragma unroll
      for (int i = 0; i < 4; ++i)
        zsB[4 * 256 + (quad * 4 + i) * 16 + m16] = accB[i];
    }
    barl();   // BAR2: zsA complete (LDS only)

    // ---- A elementwise + state stores (waves 0-1) ----
    float rha0 = 0.f, rha1 = 0.f, rca0 = 0.f, rca1 = 0.f;
    int rowA = 0, chA = 0;
    if (tid < 128) {
      const int lr = tid >> 3, cp2 = (tid & 7) * 2;
      rowA = G0a + lr; chA = C0 + cp2;
      tcell(zsA, bl, dtvA, lr, cp2, cpa0, cpa1, rha0, rha1, rca0, rca1);
      st_at32(hQ + (size_t)rowA * HSZ + chA, cvtpk(rha0, rha1));
      st_at32(cQ + (size_t)rowA * HSZ + chA, cvtpk(rca0, rca1));
    }

    // ---- B gate GEMM (waves 0-3; waves 2-3 start immediately) ----
    if (wave < 4) {
      const u16* bz = Bz + (size_t)(wave * 16 + m16) * LDBZ + quad * 8;
#pragma unroll
      for (int kt = 0; kt < 8; ++kt) {
        short8 b = *(const short8*)(bz + kt * 32);
        accB = __builtin_amdgcn_mfma_f32_16x16x32_bf16(xa8b[kt], b, accB, 0, 0, 0);
      }
      const u16* bz2 = bz + 256;
      const u16* hp  = hsB + (size_t)m16 * LDH + quad * 8;
#pragma unroll
      for (int kt = 0; kt < 16; ++kt) {
        short8 a = *(const short8*)(hp + kt * 32);
        short8 b = *(const short8*)(bz2 + kt * 32);
        accB = __builtin_amdgcn_mfma_f32_16x16x32_bf16(a, b, accB, 0, 0, 0);
      }
#pragma unroll
      for (int i = 0; i < 4; ++i)
        zsB[wave * 256 + (quad * 4 + i) * 16 + m16] = accB[i];
    }
    __syncthreads();   // BAR3: drains A state stores; zsB complete
    if (t < SEQ - 1 && tid == 0)
      st_at32((u32*)&flags[gA * 32 + cwg], (u32)(t + 1));  // A flag: early
    if (tid < 128) {
      float2 hv2; hv2.x = rha0; hv2.y = rha1;
      *(float2*)(out + ((size_t)rowA * SEQ + t) * HSZ + chA) = hv2;
      if (t == SEQ - 1) {
        float2 cv2; cv2.x = rca0; cv2.y = rca1;
        *(float2*)(out + BSH + (size_t)rowA * HSZ + chA) = hv2;       // h_t
        *(float2*)(out + BSH + BH + (size_t)rowA * HSZ + chA) = cv2;  // c_t
      }
    }

    // ---- B elementwise + state stores ----
    float rhb0 = 0.f, rhb1 = 0.f, rcb0 = 0.f, rcb1 = 0.f;
    int rowB = 0, chB = 0;
    if (tid < 128) {
      const int lr = tid >> 3, cp2 = (tid & 7) * 2;
      rowB = G0b + lr; chB = C0 + cp2;
      tcell(zsB, bl, dtvB, lr, cp2, cpb0, cpb1, rhb0, rhb1, rcb0, rcb1);
      st_at32(hQ + (size_t)rowB * HSZ + chB, cvtpk(rhb0, rhb1));
      st_at32(cQ + (size_t)rowB * HSZ + chB, cvtpk(rcb0, rcb1));
    }
    __syncthreads();   // BAR4: drains B state stores
    if (t < SEQ - 1) {
      if (tid == 0)
        st_at32((u32*)&flags[gB * 32 + cwg], (u32)(t + 1));
      // off the critical path: out_B + next-step prefetch hide under
      // peers' flag propagation + our next poll
      if (tid < 128) {
        float2 hv2; hv2.x = rhb0; hv2.y = rhb1;
        *(float2*)(out + ((size_t)rowB * SEQ + t) * HSZ + chB) = hv2;
      }
      if (wave < 4) {
        xfetch(xbA + (size_t)(t + 1) * ISZ, xa8a);
        xfetch(xbB + (size_t)(t + 1) * ISZ, xa8b);
      }
      if (tid < 128) {
        dtnA = dtp[(size_t)drA * SEQ + t + 1];
        dtnB = dtp[(size_t)drB * SEQ + t + 1];
      }
    } else {
      if (tid < 128) {
        float2 hv2; hv2.x = rhb0; hv2.y = rhb1;
        float2 cv2; cv2.x = rcb0; cv2.y = rcb1;
        *(float2*)(out + ((size_t)rowB * SEQ + t) * HSZ + chB) = hv2;
        *(float2*)(out + BSH + (size_t)rowB * HSZ + chB) = hv2;       // h_t
        *(float2*)(out + BSH + BH + (size_t)rowB * HSZ + chB) = cv2;  // c_t
      }
    }
  }
}

extern "C" void kernel_launch(void* const* d_in, const int* in_sizes, int n_in,
                              void* d_out, int out_size, void* d_ws, size_t ws_size,
                              hipStream_t stream) {
  (void)in_sizes; (void)n_in; (void)out_size; (void)ws_size;
  const float* x  = (const float*)d_in[0];
  const float* dt = (const float*)d_in[1];
  const float* W  = (const float*)d_in[2];
  const float* U  = (const float*)d_in[3];
  const float* b  = (const float*)d_in[4];
  const float* Wd = (const float*)d_in[5];
  const float* bd = (const float*)d_in[6];
  float* out = (float*)d_out;
  char*  ws  = (char*)d_ws;

  u16* wut   = (u16*)(ws + WUT_OFF);
  u16* wdt   = (u16*)(ws + WDT_OFF);
  u16* hbf   = (u16*)(ws + HBF_OFF);
  u16* cbf   = (u16*)(ws + CBF_OFF);
  int* flags = (int*)(ws + FLG_OFF);

  tlstm_prep<<<NT1 + NT2, 256, 0, stream>>>(W, U, Wd, wut, wdt, flags);

  hipFuncSetAttribute((const void*)tlstm_rec,
                      hipFuncAttributeMaxDynamicSharedMemorySize, LDS_BYTES);
  tlstm_rec<<<NPAIR * NCW, 320, LDS_BYTES, stream>>>(
      x, dt, b, bd, wut, wdt, hbf, cbf, flags, out);
}

// Round 5
// 4067.878 us; speedup vs baseline: 1.2261x; 1.1411x over previous
//
// T-LSTM persistent-recurrence kernel for MI355X (gfx950) — round 7.
//
// Round 6 post-mortem: group pairing LENGTHENED the chain (4642 us) —
// both groups' phases serialize on the same waves and both gate every
// peer's poll. Reverted to round-3 structure (8 groups x 32 col-WGs,
// 3083 us best).
//
// Round 7: shorten the round-3 per-step chain by deleting the h LDS
// staging + its barrier. Gate waves load their h MFMA A-fragments
// DIRECTLY from global (same proven pattern as the c_s wave's c loads);
// the 4x redundant reads cost only MALL bandwidth (3.5% utilized — free),
// while the chain loses a full __syncthreads + LDS write/read hop. The
// x@W GEMM (operands prefetched in the previous step's shadow) issues
// after the h loads and covers part of their latency. One LDS-only
// barrier (zs ready) + one pre-flag drain remain per step. Cell fp32
// master state in registers (proven round 6).

#include <hip/hip_runtime.h>

typedef unsigned short u16;
typedef unsigned int u32;
typedef unsigned long long u64;
typedef __attribute__((ext_vector_type(8))) short short8;
typedef __attribute__((ext_vector_type(4))) float f32x4;

constexpr int BATCH = 128, SEQ = 512, ISZ = 256, HSZ = 512, G4H = 2048;
constexpr int KZ   = ISZ + HSZ;                 // 768
constexpr int NGRP = 8,  MR  = BATCH / NGRP;    // 16 rows per group
constexpr int NCW  = 32, CPW = HSZ / NCW;       // 16 cols per WG
constexpr int LDBZ = KZ + 8, LDBC = HSZ + 8;
constexpr int BH   = BATCH * HSZ;               // 65536
constexpr size_t BSH = (size_t)BATCH * SEQ * HSZ;

// workspace layout (bytes)
constexpr size_t WUT_OFF = 0;                                  // 2048*768*2
constexpr size_t WDT_OFF = WUT_OFF + (size_t)G4H * KZ * 2;     // 512*512*2
constexpr size_t HBF_OFF = WDT_OFF + (size_t)HSZ * HSZ * 2;    // h bf16 x2
constexpr size_t CBF_OFF = HBF_OFF + (size_t)2 * BH * 2;       // c bf16 x2
constexpr size_t FLG_OFF = CBF_OFF + (size_t)2 * BH * 2;       // 256 ints

// LDS layout (bytes)
constexpr int BZ_OFF  = 0;                       // [64][LDBZ] u16
constexpr int BC_OFF  = BZ_OFF  + 64 * LDBZ * 2; // [16][LDBC] u16
constexpr int ZS_OFF  = BC_OFF  + 16 * LDBC * 2; // [5][16][16] f32
constexpr int BL_OFF  = ZS_OFF  + 5 * 256 * 4;   // [5][16] f32
constexpr int LDS_BYTES = BL_OFF + 5 * CPW * 4;  // 121728

__device__ __forceinline__ u16 f2bf(float f) {
  unsigned u = __float_as_uint(f);
  u += 0x7fffu + ((u >> 16) & 1u);   // RNE
  return (u16)(u >> 16);
}

// hardware packed f32x2 -> bf16x2 (RNE), lo in bits [15:0]
__device__ __forceinline__ u32 cvtpk(float lo, float hi) {
  u32 r;
  asm("v_cvt_pk_bf16_f32 %0, %1, %2" : "=v"(r) : "v"(lo), "v"(hi));
  return r;
}

__device__ __forceinline__ short8 cvt_bf8(float4 a, float4 b) {
  union { u32 u[4]; short8 s; } v;
  v.u[0] = cvtpk(a.x, a.y);
  v.u[1] = cvtpk(a.z, a.w);
  v.u[2] = cvtpk(b.x, b.y);
  v.u[3] = cvtpk(b.z, b.w);
  return v.s;
}

__device__ __forceinline__ u64 ld_at64(const void* p) {
  return __hip_atomic_load((const u64*)p, __ATOMIC_RELAXED,
                           __HIP_MEMORY_SCOPE_AGENT);
}
__device__ __forceinline__ void st_at64(void* p, u64 v) {
  __hip_atomic_store((u64*)p, v, __ATOMIC_RELAXED, __HIP_MEMORY_SCOPE_AGENT);
}
__device__ __forceinline__ void st_at32(void* p, u32 v) {
  __hip_atomic_store((u32*)p, v, __ATOMIC_RELAXED, __HIP_MEMORY_SCOPE_AGENT);
}
__device__ __forceinline__ int ld_ati(const int* p) {
  return __hip_atomic_load(p, __ATOMIC_RELAXED, __HIP_MEMORY_SCOPE_AGENT);
}
__device__ __forceinline__ short8 ld_bf8_at(const u16* p) {
  union { u64 u[2]; short8 s; } v;
  v.u[0] = ld_at64(p);
  v.u[1] = ld_at64(p + 4);
  return v.s;
}

__device__ __forceinline__ float sig_f(float x)  { return 1.f / (1.f + __expf(-x)); }
__device__ __forceinline__ float tanh_f(float x) { return 1.f - 2.f / (1.f + __expf(2.f * x)); }

// raw barrier: LDS visibility only (no vmem-ack drain on the chain)
__device__ __forceinline__ void barl() {
  asm volatile("s_waitcnt lgkmcnt(0)" ::: "memory");
  __builtin_amdgcn_s_barrier();
  __builtin_amdgcn_sched_barrier(0);
}

// batched x-row fetch + bf16 convert (16 float4 issued back-to-back)
__device__ __forceinline__ void xfetch(const float* xp, short8* xa8) {
  float4 xf[16];
#pragma unroll
  for (int kt = 0; kt < 8; ++kt) {
    xf[2 * kt]     = *(const float4*)(xp + kt * 32);
    xf[2 * kt + 1] = *(const float4*)(xp + kt * 32 + 4);
  }
#pragma unroll
  for (int kt = 0; kt < 8; ++kt)
    xa8[kt] = cvt_bf8(xf[2 * kt], xf[2 * kt + 1]);
}

// ---- prep: tiled transpose W||U -> wut (2048x768 bf16), Wd -> wdt ----
constexpr int TJ1 = G4H / 32;       // 64
constexpr int TK1 = KZ / 32;        // 24
constexpr int NT1 = TJ1 * TK1;      // 1536
constexpr int TJ2 = HSZ / 32;       // 16
constexpr int NT2 = TJ2 * TJ2;      // 256

__global__ void tlstm_prep(const float* __restrict__ W, const float* __restrict__ U,
                           const float* __restrict__ Wd,
                           u16* __restrict__ wut, u16* __restrict__ wdt,
                           int* __restrict__ flags) {
  __shared__ float tb[32][33];
  const int tid = threadIdx.x;
  const int c = tid & 31, r = tid >> 5;       // 256 thr: r 0..7
  const int tile = blockIdx.x;
  if (tile == 0 && tid < 256) flags[tid] = 0; // deterministic sync state
  if (tile < NT1) {
    const int tj = tile % TJ1, tk = tile / TJ1;
    const int j0 = tj * 32, k0 = tk * 32;
#pragma unroll
    for (int rr = r; rr < 32; rr += 8) {
      const int k = k0 + rr;
      tb[rr][c] = (k < ISZ) ? W[(size_t)k * G4H + j0 + c]
                            : U[(size_t)(k - ISZ) * G4H + j0 + c];
    }
    __syncthreads();
#pragma unroll
    for (int rr = r; rr < 32; rr += 8)
      wut[(size_t)(j0 + rr) * KZ + k0 + c] = f2bf(tb[c][rr]);
  } else {
    const int t2 = tile - NT1;
    const int tj = t2 % TJ2, tk = t2 / TJ2;
    const int j0 = tj * 32, k0 = tk * 32;
#pragma unroll
    for (int rr = r; rr < 32; rr += 8)
      tb[rr][c] = Wd[(size_t)(k0 + rr) * HSZ + j0 + c];
    __syncthreads();
#pragma unroll
    for (int rr = r; rr < 32; rr += 8)
      wdt[(size_t)(j0 + rr) * HSZ + k0 + c] = f2bf(tb[c][rr]);
  }
}

__global__ void __launch_bounds__(320, 1)
tlstm_rec(const float* __restrict__ x, const float* __restrict__ dtp,
          const float* __restrict__ bias, const float* __restrict__ bd,
          const u16* __restrict__ wut, const u16* __restrict__ wdt,
          u16* hbf, u16* cbf, int* flags, float* out) {
  extern __shared__ char lds[];
  u16*   Bz  = (u16*)(lds + BZ_OFF);
  u16*   Bc  = (u16*)(lds + BC_OFF);
  float* zs  = (float*)(lds + ZS_OFF);
  float* bl  = (float*)(lds + BL_OFF);

  const int tid  = threadIdx.x;
  const int grp  = blockIdx.x >> 5;     // batch group 0..7
  const int cwg  = blockIdx.x & 31;     // column WG 0..31
  const int G0   = grp * MR;
  const int C0   = cwg * CPW;
  const int wave = tid >> 6, lane = tid & 63;
  const int m16  = lane & 15, quad = lane >> 4;

  // ---- stage weights into LDS (once) ----
  {
    const unsigned* src = (const unsigned*)wut;
    unsigned* dst = (unsigned*)Bz;
    for (int i = tid; i < 64 * (KZ / 2); i += 320) {
      int gc = i / (KZ / 2), d = i - gc * (KZ / 2);
      int zc = (gc >> 4) * HSZ + C0 + (gc & 15);   // gate-major z column
      dst[gc * (LDBZ / 2) + d] = src[zc * (KZ / 2) + d];
    }
    const unsigned* s2 = (const unsigned*)wdt;
    unsigned* d2 = (unsigned*)Bc;
    for (int i = tid; i < 16 * (HSZ / 2); i += 320) {
      int r = i >> 8, d = i & 255;
      d2[r * (LDBC / 2) + d] = s2[(C0 + r) * (HSZ / 2) + d];
    }
  }
  // biases -> LDS
  if (tid < 80) {
    int j = tid >> 4, c = tid & 15;
    bl[tid] = (j < 4) ? bias[j * HSZ + C0 + c] : bd[C0 + c];
  }
  // zero group's state rows in buffer 0 (all col-WGs write same zeros;
  // each WG writes its own full copy -> t=0 needs no peer flag)
  {
    u64* h0 = (u64*)(hbf + (size_t)G0 * HSZ);
    u64* c0 = (u64*)(cbf + (size_t)G0 * HSZ);
    for (int i = tid; i < MR * HSZ / 4; i += 320) {
      st_at64(h0 + i, 0ull);
      st_at64(c0 + i, 0ull);
    }
  }
  __syncthreads();   // drains vmcnt: zeros at MALL before t=0 reads

  const int* fbase = flags + grp * 32;
  const float* xbase = x + (size_t)(G0 + m16) * SEQ * ISZ + quad * 8;
  const int drow = G0 + (tid >> 3);

  // prologue prefetch for t = 0
  short8 xa8[8];
  float dtn = 0.f;
  if (wave < 4) xfetch(xbase, xa8);
  if (tid < 128) dtn = dtp[(size_t)drow * SEQ];
  // fp32 cell master state: thread-private registers (2 cols per thread)
  float cm0 = 0.f, cm1 = 0.f;

  for (int t = 0; t < SEQ; ++t) {
    const int p = t & 1, q = p ^ 1;
    const u16* hA = hbf + (size_t)p * BH;
    const u16* cA = cbf + (size_t)p * BH;
    u16* hQ = hbf + (size_t)q * BH;
    u16* cQ = cbf + (size_t)q * BH;
    const float dtv = dtn;

    f32x4 acc = {0.f, 0.f, 0.f, 0.f};

    if (wave < 4) {
      // gate wave: load h A-fragments DIRECTLY from global (no LDS hop)
      const u16* hp = hA + (size_t)(G0 + m16) * HSZ + quad * 8;
      short8 hf[16];
#pragma unroll
      for (int kt = 0; kt < 16; ++kt)
        hf[kt] = ld_bf8_at(hp + kt * 32);
      // x@W (regs + LDS weights) issues while h loads fly
      const u16* bz = Bz + (size_t)(wave * 16 + m16) * LDBZ + quad * 8;
#pragma unroll
      for (int kt = 0; kt < 8; ++kt) {
        short8 b = *(const short8*)(bz + kt * 32);
        acc = __builtin_amdgcn_mfma_f32_16x16x32_bf16(xa8[kt], b, acc, 0, 0, 0);
      }
      // h@U directly from registers
      const u16* bz2 = bz + 256;
#pragma unroll
      for (int kt = 0; kt < 16; ++kt) {
        short8 b = *(const short8*)(bz2 + kt * 32);
        acc = __builtin_amdgcn_mfma_f32_16x16x32_bf16(hf[kt], b, acc, 0, 0, 0);
      }
#pragma unroll
      for (int i = 0; i < 4; ++i)
        zs[wave * 256 + (quad * 4 + i) * 16 + m16] = acc[i];
    } else {
      // c_s wave: c A-fragments direct from global, GEMM vs Bc
      const u16* cp = cA + (size_t)(G0 + m16) * HSZ + quad * 8;
      short8 ca[16];
#pragma unroll
      for (int kt = 0; kt < 16; ++kt)
        ca[kt] = ld_bf8_at(cp + kt * 32);
      const u16* bc = Bc + (size_t)m16 * LDBC + quad * 8;
#pragma unroll
      for (int kt = 0; kt < 16; ++kt) {
        short8 b = *(const short8*)(bc + kt * 32);
        acc = __builtin_amdgcn_mfma_f32_16x16x32_bf16(ca[kt], b, acc, 0, 0, 0);
      }
#pragma unroll
      for (int i = 0; i < 4; ++i)
        zs[4 * 256 + (quad * 4 + i) * 16 + m16] = acc[i];
    }
    barl();   // zs complete (LDS-only barrier; no vmem drain on chain)

    // ---- element-wise T-LSTM update: 16 rows x 16 cols, col-pairs ----
    float rh0 = 0.f, rh1 = 0.f, rc0 = 0.f, rc1 = 0.f;
    int row = 0, ch = 0;
    if (tid < 128) {
      const int lr  = tid >> 3;          // local row 0..15
      const int cp2 = (tid & 7) * 2;     // even local col
      row = G0 + lr;
      ch  = C0 + cp2;
      const float gdec = 1.f / __logf(2.718281828459045f + dtv);
      float rh[2], rc[2];
#pragma unroll
      for (int u = 0; u < 2; ++u) {
        const int c = cp2 + u;
        const int zb = lr * 16 + c;
        float zi = zs[0 * 256 + zb] + bl[0 * 16 + c];
        float zf = zs[1 * 256 + zb] + bl[1 * 16 + c];
        float zo = zs[2 * 256 + zb] + bl[2 * 16 + c];
        float zc = zs[3 * 256 + zb] + bl[3 * 16 + c];
        float s  = zs[4 * 256 + zb] + bl[4 * 16 + c];
        float cprev = u ? cm1 : cm0;
        float cs = tanh_f(s);
        float cadj = cprev - cs + cs * gdec;
        float ig = sig_f(zi), fg = sig_f(zf), og = sig_f(zo);
        float ct = tanh_f(zc);
        float cnew = fg * cadj + ig * ct;
        float hnew = og * tanh_f(cnew);
        if (u) { cm1 = cnew; rh1 = hnew; rc1 = cnew; }
        else   { cm0 = cnew; rh0 = hnew; rc0 = cnew; }
      }
      // state stores: the only thing the pre-flag drain must cover
      st_at32(hQ + (size_t)row * HSZ + ch, cvtpk(rh0, rh1));
      st_at32(cQ + (size_t)row * HSZ + ch, cvtpk(rc0, rc1));
    }

    // ---- fence-free per-group barrier ----
    if (t < SEQ - 1) {
      __syncthreads();   // state stores drained (vmcnt 0)
      __asm__ volatile("" ::: "memory");
      if (tid == 0)
        st_at32((u32*)&flags[grp * 32 + cwg], (u32)(t + 2));
      // off the critical path: hide under peers' flag propagation + poll
      if (tid < 128) {
        float2 hv2; hv2.x = rh0; hv2.y = rh1;
        *(float2*)(out + ((size_t)row * SEQ + t) * HSZ + ch) = hv2;
      }
      if (wave < 4)
        xfetch(xbase + (size_t)(t + 1) * ISZ, xa8);
      if (tid < 128)
        dtn = dtp[(size_t)drow * SEQ + t + 1];
      for (int gu = 0; ; ++gu) {
        int v = (lane < 32) ? ld_ati(fbase + lane) : 0x7fffffff;
        if (__all(v >= t + 2)) break;
        if (gu > (1 << 22)) break;      // hang insurance: fail visibly
        __builtin_amdgcn_s_sleep(1);
      }
      __asm__ volatile("" ::: "memory");
    } else {
      if (tid < 128) {
        float2 hv2; hv2.x = rh0; hv2.y = rh1;
        float2 cv2; cv2.x = rc0; cv2.y = rc1;
        *(float2*)(out + ((size_t)row * SEQ + t) * HSZ + ch) = hv2;
        *(float2*)(out + BSH + (size_t)row * HSZ + ch) = hv2;       // h_t
        *(float2*)(out + BSH + BH + (size_t)row * HSZ + ch) = cv2;  // c_t
      }
    }
  }
}

extern "C" void kernel_launch(void* const* d_in, const int* in_sizes, int n_in,
                              void* d_out, int out_size, void* d_ws, size_t ws_size,
                              hipStream_t stream) {
  (void)in_sizes; (void)n_in; (void)out_size; (void)ws_size;
  const float* x  = (const float*)d_in[0];
  const float* dt = (const float*)d_in[1];
  const float* W  = (const float*)d_in[2];
  const float* U  = (const float*)d_in[3];
  const float* b  = (const float*)d_in[4];
  const float* Wd = (const float*)d_in[5];
  const float* bd = (const float*)d_in[6];
  float* out = (float*)d_out;
  char*  ws  = (char*)d_ws;

  u16* wut   = (u16*)(ws + WUT_OFF);
  u16* wdt   = (u16*)(ws + WDT_OFF);
  u16* hbf   = (u16*)(ws + HBF_OFF);
  u16* cbf   = (u16*)(ws + CBF_OFF);
  int* flags = (int*)(ws + FLG_OFF);

  tlstm_prep<<<NT1 + NT2, 256, 0, stream>>>(W, U, Wd, wut, wdt, flags);

  hipFuncSetAttribute((const void*)tlstm_rec,
                      hipFuncAttributeMaxDynamicSharedMemorySize, LDS_BYTES);
  tlstm_rec<<<NGRP * NCW, 320, LDS_BYTES, stream>>>(
      x, dt, b, bd, wut, wdt, hbf, cbf, flags, out);
}

// Round 6
// 2639.023 us; speedup vs baseline: 1.8899x; 1.5414x over previous
//
// T-LSTM persistent-recurrence kernel for MI355X (gfx950) — round 8.
//
// Round 7 post-mortem: direct (non-deduplicated) h loads cost +1 us/step
// -> agent-scope traffic is REQUEST-THROUGHPUT bound at MALL (every WG
// bursts simultaneously each step; 8B requests queue). Staging + its
// barrier earn their keep; the lever is fewer, wider requests.
//
// Round 8 (base = round-3 structure, 3083 us best):
//  - ALL agent state loads widened to global_load_dwordx4 sc0 sc1 (16B):
//    h-stage 4x dwordx4/thread, c_s 16x dwordx4/lane -> per-WG request
//    count halved (4096 -> 2048).
//  - intra-step barriers are LDS-only (lgkmcnt+s_barrier); only the
//    pre-flag barrier drains vmem (the 2 state stores).
//  - kept from r7 (verified): register fp32 cell state, x/dt prefetch in
//    the poll shadow, out-stores after the flag store.
//  - explicit s_waitcnt vmcnt(0) + sched_barrier before consuming
//    asm-loaded regs (compiler can't see asm loads' vmcnt).

#include <hip/hip_runtime.h>

typedef unsigned short u16;
typedef unsigned int u32;
typedef unsigned long long u64;
typedef __attribute__((ext_vector_type(8))) short short8;
typedef __attribute__((ext_vector_type(4))) float f32x4;
typedef __attribute__((ext_vector_type(4))) unsigned int u32x4;

constexpr int BATCH = 128, SEQ = 512, ISZ = 256, HSZ = 512, G4H = 2048;
constexpr int KZ   = ISZ + HSZ;                 // 768
constexpr int NGRP = 8,  MR  = BATCH / NGRP;    // 16 rows per group
constexpr int NCW  = 32, CPW = HSZ / NCW;       // 16 cols per WG
constexpr int LDBZ = KZ + 8, LDBC = HSZ + 8, LDH = HSZ + 8;
constexpr int BH   = BATCH * HSZ;               // 65536
constexpr size_t BSH = (size_t)BATCH * SEQ * HSZ;

// workspace layout (bytes)
constexpr size_t WUT_OFF = 0;                                  // 2048*768*2
constexpr size_t WDT_OFF = WUT_OFF + (size_t)G4H * KZ * 2;     // 512*512*2
constexpr size_t HBF_OFF = WDT_OFF + (size_t)HSZ * HSZ * 2;    // h bf16 x2
constexpr size_t CBF_OFF = HBF_OFF + (size_t)2 * BH * 2;       // c bf16 x2
constexpr size_t FLG_OFF = CBF_OFF + (size_t)2 * BH * 2;       // 256 ints

// LDS layout (bytes)
constexpr int BZ_OFF  = 0;                       // [64][LDBZ] u16
constexpr int BC_OFF  = BZ_OFF  + 64 * LDBZ * 2; // [16][LDBC] u16
constexpr int HS_OFF  = BC_OFF  + 16 * LDBC * 2; // [MR][LDH]  u16
constexpr int ZS_OFF  = HS_OFF  + MR * LDH * 2;  // [5][16][16] f32
constexpr int BL_OFF  = ZS_OFF  + 5 * 256 * 4;   // [5][16] f32
constexpr int LDS_BYTES = BL_OFF + 5 * CPW * 4;  // 138368

__device__ __forceinline__ u16 f2bf(float f) {
  unsigned u = __float_as_uint(f);
  u += 0x7fffu + ((u >> 16) & 1u);   // RNE
  return (u16)(u >> 16);
}

// hardware packed f32x2 -> bf16x2 (RNE), lo in bits [15:0]
__device__ __forceinline__ u32 cvtpk(float lo, float hi) {
  u32 r;
  asm("v_cvt_pk_bf16_f32 %0, %1, %2" : "=v"(r) : "v"(lo), "v"(hi));
  return r;
}

__device__ __forceinline__ short8 cvt_bf8(float4 a, float4 b) {
  union { u32 u[4]; short8 s; } v;
  v.u[0] = cvtpk(a.x, a.y);
  v.u[1] = cvtpk(a.z, a.w);
  v.u[2] = cvtpk(b.x, b.y);
  v.u[3] = cvtpk(b.z, b.w);
  return v.s;
}

// 16B agent-coherent load (sc0 sc1 = bypass L1 + non-coherent L2, MALL)
__device__ __forceinline__ u32x4 ld_at128(const void* p) {
  u32x4 r;
  asm volatile("global_load_dwordx4 %0, %1, off sc0 sc1"
               : "=v"(r) : "v"(p));
  return r;
}

__device__ __forceinline__ void st_at64(void* p, u64 v) {
  __hip_atomic_store((u64*)p, v, __ATOMIC_RELAXED, __HIP_MEMORY_SCOPE_AGENT);
}
__device__ __forceinline__ void st_at32(void* p, u32 v) {
  __hip_atomic_store((u32*)p, v, __ATOMIC_RELAXED, __HIP_MEMORY_SCOPE_AGENT);
}
__device__ __forceinline__ int ld_ati(const int* p) {
  return __hip_atomic_load(p, __ATOMIC_RELAXED, __HIP_MEMORY_SCOPE_AGENT);
}

__device__ __forceinline__ float sig_f(float x)  { return 1.f / (1.f + __expf(-x)); }
__device__ __forceinline__ float tanh_f(float x) { return 1.f - 2.f / (1.f + __expf(2.f * x)); }

// drain outstanding asm vmem loads, keep consumers below
__device__ __forceinline__ void wait_vm0() {
  asm volatile("s_waitcnt vmcnt(0)" ::: "memory");
  __builtin_amdgcn_sched_barrier(0);
}

// raw barrier: LDS visibility only (no vmem-ack drain on the chain)
__device__ __forceinline__ void barl() {
  asm volatile("s_waitcnt lgkmcnt(0)" ::: "memory");
  __builtin_amdgcn_s_barrier();
  __builtin_amdgcn_sched_barrier(0);
}

// batched x-row fetch + bf16 convert (16 float4 issued back-to-back)
__device__ __forceinline__ void xfetch(const float* xp, short8* xa8) {
  float4 xf[16];
#pragma unroll
  for (int kt = 0; kt < 8; ++kt) {
    xf[2 * kt]     = *(const float4*)(xp + kt * 32);
    xf[2 * kt + 1] = *(const float4*)(xp + kt * 32 + 4);
  }
#pragma unroll
  for (int kt = 0; kt < 8; ++kt)
    xa8[kt] = cvt_bf8(xf[2 * kt], xf[2 * kt + 1]);
}

// ---- prep: tiled transpose W||U -> wut (2048x768 bf16), Wd -> wdt ----
constexpr int TJ1 = G4H / 32;       // 64
constexpr int TK1 = KZ / 32;        // 24
constexpr int NT1 = TJ1 * TK1;      // 1536
constexpr int TJ2 = HSZ / 32;       // 16
constexpr int NT2 = TJ2 * TJ2;      // 256

__global__ void tlstm_prep(const float* __restrict__ W, const float* __restrict__ U,
                           const float* __restrict__ Wd,
                           u16* __restrict__ wut, u16* __restrict__ wdt,
                           int* __restrict__ flags) {
  __shared__ float tb[32][33];
  const int tid = threadIdx.x;
  const int c = tid & 31, r = tid >> 5;       // 256 thr: r 0..7
  const int tile = blockIdx.x;
  if (tile == 0 && tid < 256) flags[tid] = 0; // deterministic sync state
  if (tile < NT1) {
    const int tj = tile % TJ1, tk = tile / TJ1;
    const int j0 = tj * 32, k0 = tk * 32;
#pragma unroll
    for (int rr = r; rr < 32; rr += 8) {
      const int k = k0 + rr;
      tb[rr][c] = (k < ISZ) ? W[(size_t)k * G4H + j0 + c]
                            : U[(size_t)(k - ISZ) * G4H + j0 + c];
    }
    __syncthreads();
#pragma unroll
    for (int rr = r; rr < 32; rr += 8)
      wut[(size_t)(j0 + rr) * KZ + k0 + c] = f2bf(tb[c][rr]);
  } else {
    const int t2 = tile - NT1;
    const int tj = t2 % TJ2, tk = t2 / TJ2;
    const int j0 = tj * 32, k0 = tk * 32;
#pragma unroll
    for (int rr = r; rr < 32; rr += 8)
      tb[rr][c] = Wd[(size_t)(k0 + rr) * HSZ + j0 + c];
    __syncthreads();
#pragma unroll
    for (int rr = r; rr < 32; rr += 8)
      wdt[(size_t)(j0 + rr) * HSZ + k0 + c] = f2bf(tb[c][rr]);
  }
}

__global__ void __launch_bounds__(320, 1)
tlstm_rec(const float* __restrict__ x, const float* __restrict__ dtp,
          const float* __restrict__ bias, const float* __restrict__ bd,
          const u16* __restrict__ wut, const u16* __restrict__ wdt,
          u16* hbf, u16* cbf, int* flags, float* out) {
  extern __shared__ char lds[];
  u16*   Bz  = (u16*)(lds + BZ_OFF);
  u16*   Bc  = (u16*)(lds + BC_OFF);
  u16*   hs  = (u16*)(lds + HS_OFF);
  float* zs  = (float*)(lds + ZS_OFF);
  float* bl  = (float*)(lds + BL_OFF);

  const int tid  = threadIdx.x;
  const int grp  = blockIdx.x >> 5;     // batch group 0..7
  const int cwg  = blockIdx.x & 31;     // column WG 0..31
  const int G0   = grp * MR;
  const int C0   = cwg * CPW;
  const int wave = tid >> 6, lane = tid & 63;
  const int m16  = lane & 15, quad = lane >> 4;

  // ---- stage weights into LDS (once) ----
  {
    const unsigned* src = (const unsigned*)wut;
    unsigned* dst = (unsigned*)Bz;
    for (int i = tid; i < 64 * (KZ / 2); i += 320) {
      int gc = i / (KZ / 2), d = i - gc * (KZ / 2);
      int zc = (gc >> 4) * HSZ + C0 + (gc & 15);   // gate-major z column
      dst[gc * (LDBZ / 2) + d] = src[zc * (KZ / 2) + d];
    }
    const unsigned* s2 = (const unsigned*)wdt;
    unsigned* d2 = (unsigned*)Bc;
    for (int i = tid; i < 16 * (HSZ / 2); i += 320) {
      int r = i >> 8, d = i & 255;
      d2[r * (LDBC / 2) + d] = s2[(C0 + r) * (HSZ / 2) + d];
    }
  }
  // biases -> LDS
  if (tid < 80) {
    int j = tid >> 4, c = tid & 15;
    bl[tid] = (j < 4) ? bias[j * HSZ + C0 + c] : bd[C0 + c];
  }
  // zero group's state rows in buffer 0 (all col-WGs write same zeros)
  {
    u64* h0 = (u64*)(hbf + (size_t)G0 * HSZ);
    u64* c0 = (u64*)(cbf + (size_t)G0 * HSZ);
    for (int i = tid; i < MR * HSZ / 4; i += 320) {
      st_at64(h0 + i, 0ull);
      st_at64(c0 + i, 0ull);
    }
  }
  __syncthreads();   // drains vmcnt: zeros at MALL before t=0 reads

  const int* fbase = flags + grp * 32;
  const float* xbase = x + (size_t)(G0 + m16) * SEQ * ISZ + quad * 8;
  const int drow = G0 + (tid >> 3);

  // prologue prefetch for t = 0
  short8 xa8[8];
  float dtn = 0.f;
  if (wave < 4) xfetch(xbase, xa8);
  if (tid < 128) dtn = dtp[(size_t)drow * SEQ];
  // fp32 cell master state: thread-private registers (2 cols per thread)
  float cm0 = 0.f, cm1 = 0.f;

  for (int t = 0; t < SEQ; ++t) {
    const int p = t & 1, q = p ^ 1;
    const u16* hA = hbf + (size_t)p * BH;
    const u16* cA = cbf + (size_t)p * BH;
    u16* hQ = hbf + (size_t)q * BH;
    u16* cQ = cbf + (size_t)q * BH;
    const float dtv = dtn;

    f32x4 acc = {0.f, 0.f, 0.f, 0.f};

    if (wave < 4) {
      // ---- de-dup h stage, 16B requests: 256 thr x 4 dwordx4 ----
      const char* hsrc = (const char*)(hA + (size_t)G0 * HSZ);
      u32x4 hv[4];
#pragma unroll
      for (int j = 0; j < 4; ++j) {
        int i = tid + j * 256;                     // 16B unit index
        hv[j] = ld_at128(hsrc + (i >> 6) * 1024 + (i & 63) * 16);
      }
      // x@W (regs + LDS weights) while h loads fly
      const u16* bz = Bz + (size_t)(wave * 16 + m16) * LDBZ + quad * 8;
#pragma unroll
      for (int kt = 0; kt < 8; ++kt) {
        short8 b = *(const short8*)(bz + kt * 32);
        acc = __builtin_amdgcn_mfma_f32_16x16x32_bf16(xa8[kt], b, acc, 0, 0, 0);
      }
      wait_vm0();
#pragma unroll
      for (int j = 0; j < 4; ++j) {
        int i = tid + j * 256;
        *(u32x4*)((char*)hs + (i >> 6) * (LDH * 2) + (i & 63) * 16) = hv[j];
      }
    } else {
      // ---- c_s wave: 16 dwordx4 frag loads, then GEMM vs Bc ----
      const char* cp =
          (const char*)(cA + (size_t)(G0 + m16) * HSZ) + quad * 16;
      union { u32x4 u; short8 s; } ca[16];
#pragma unroll
      for (int kt = 0; kt < 16; ++kt)
        ca[kt].u = ld_at128(cp + kt * 64);
      wait_vm0();
      const u16* bc = Bc + (size_t)m16 * LDBC + quad * 8;
#pragma unroll
      for (int kt = 0; kt < 16; ++kt) {
        short8 b = *(const short8*)(bc + kt * 32);
        acc = __builtin_amdgcn_mfma_f32_16x16x32_bf16(ca[kt].s, b, acc, 0, 0, 0);
      }
#pragma unroll
      for (int i = 0; i < 4; ++i)
        zs[4 * 256 + (quad * 4 + i) * 16 + m16] = acc[i];
    }
    barl();   // BAR1 (LDS-only): hs staged, zs[4] written

    if (wave < 4) {
      // h@U from LDS
      const u16* bz2 = Bz + (size_t)(wave * 16 + m16) * LDBZ + 256 + quad * 8;
      const u16* hp  = hs + (size_t)m16 * LDH + quad * 8;
#pragma unroll
      for (int kt = 0; kt < 16; ++kt) {
        short8 a = *(const short8*)(hp + kt * 32);
        short8 b = *(const short8*)(bz2 + kt * 32);
        acc = __builtin_amdgcn_mfma_f32_16x16x32_bf16(a, b, acc, 0, 0, 0);
      }
#pragma unroll
      for (int i = 0; i < 4; ++i)
        zs[wave * 256 + (quad * 4 + i) * 16 + m16] = acc[i];
    }
    barl();   // BAR2 (LDS-only): zs complete

    // ---- element-wise T-LSTM update: 16 rows x 16 cols, col-pairs ----
    float rh0 = 0.f, rh1 = 0.f, rc0 = 0.f, rc1 = 0.f;
    int row = 0, ch = 0;
    if (tid < 128) {
      const int lr  = tid >> 3;          // local row 0..15
      const int cp2 = (tid & 7) * 2;     // even local col
      row = G0 + lr;
      ch  = C0 + cp2;
      const float gdec = 1.f / __logf(2.718281828459045f + dtv);
      float rh[2], rc[2];
#pragma unroll
      for (int u = 0; u < 2; ++u) {
        const int c = cp2 + u;
        const int zb = lr * 16 + c;
        float zi = zs[0 * 256 + zb] + bl[0 * 16 + c];
        float zf = zs[1 * 256 + zb] + bl[1 * 16 + c];
        float zo = zs[2 * 256 + zb] + bl[2 * 16 + c];
        float zc = zs[3 * 256 + zb] + bl[3 * 16 + c];
        float s  = zs[4 * 256 + zb] + bl[4 * 16 + c];
        float cprev = u ? cm1 : cm0;
        float cs = tanh_f(s);
        float cadj = cprev - cs + cs * gdec;
        float ig = sig_f(zi), fg = sig_f(zf), og = sig_f(zo);
        float ct = tanh_f(zc);
        float cnew = fg * cadj + ig * ct;
        float hnew = og * tanh_f(cnew);
        if (u) { cm1 = cnew; rh1 = hnew; rc1 = cnew; }
        else   { cm0 = cnew; rh0 = hnew; rc0 = cnew; }
      }
      // state stores: the only thing the pre-flag drain must cover
      st_at32(hQ + (size_t)row * HSZ + ch, cvtpk(rh0, rh1));
      st_at32(cQ + (size_t)row * HSZ + ch, cvtpk(rc0, rc1));
    }

    // ---- fence-free per-group barrier ----
    if (t < SEQ - 1) {
      __syncthreads();   // state stores drained (vmcnt 0)
      __asm__ volatile("" ::: "memory");
      if (tid == 0)
        st_at32((u32*)&flags[grp * 32 + cwg], (u32)(t + 2));
      // off the critical path: hide under peers' flag propagation + poll
      if (tid < 128) {
        float2 hv2; hv2.x = rh0; hv2.y = rh1;
        *(float2*)(out + ((size_t)row * SEQ + t) * HSZ + ch) = hv2;
      }
      if (wave < 4)
        xfetch(xbase + (size_t)(t + 1) * ISZ, xa8);
      if (tid < 128)
        dtn = dtp[(size_t)drow * SEQ + t + 1];
      for (int gu = 0; ; ++gu) {
        int v = (lane < 32) ? ld_ati(fbase + lane) : 0x7fffffff;
        if (__all(v >= t + 2)) break;
        if (gu > (1 << 22)) break;      // hang insurance: fail visibly
        __builtin_amdgcn_s_sleep(1);
      }
      __asm__ volatile("" ::: "memory");
    } else {
      if (tid < 128) {
        float2 hv2; hv2.x = rh0; hv2.y = rh1;
        float2 cv2; cv2.x = rc0; cv2.y = rc1;
        *(float2*)(out + ((size_t)row * SEQ + t) * HSZ + ch) = hv2;
        *(float2*)(out + BSH + (size_t)row * HSZ + ch) = hv2;       // h_t
        *(float2*)(out + BSH + BH + (size_t)row * HSZ + ch) = cv2;  // c_t
      }
    }
  }
}

extern "C" void kernel_launch(void* const* d_in, const int* in_sizes, int n_in,
                              void* d_out, int out_size, void* d_ws, size_t ws_size,
                              hipStream_t stream) {
  (void)in_sizes; (void)n_in; (void)out_size; (void)ws_size;
  const float* x  = (const float*)d_in[0];
  const float* dt = (const float*)d_in[1];
  const float* W  = (const float*)d_in[2];
  const float* U  = (const float*)d_in[3];
  const float* b  = (const float*)d_in[4];
  const float* Wd = (const float*)d_in[5];
  const float* bd = (const float*)d_in[6];
  float* out = (float*)d_out;
  char*  ws  = (char*)d_ws;

  u16* wut   = (u16*)(ws + WUT_OFF);
  u16* wdt   = (u16*)(ws + WDT_OFF);
  u16* hbf   = (u16*)(ws + HBF_OFF);
  u16* cbf   = (u16*)(ws + CBF_OFF);
  int* flags = (int*)(ws + FLG_OFF);

  tlstm_prep<<<NT1 + NT2, 256, 0, stream>>>(W, U, Wd, wut, wdt, flags);

  hipFuncSetAttribute((const void*)tlstm_rec,
                      hipFuncAttributeMaxDynamicSharedMemorySize, LDS_BYTES);
  tlstm_rec<<<NGRP * NCW, 320, LDS_BYTES, stream>>>(
      x, dt, b, bd, wut, wdt, hbf, cbf, flags, out);
}